// Round 9
// baseline (650.631 us; speedup 1.0000x reference)
//
#include <hip/hip_runtime.h>
#include <stdint.h>
#include <stddef.h>

#define BB     16384
#define TD     768
#define ID_    1024
#define HID    1024
#define OD     1024
#define NE     8
#define CB     2048
#define CAPT   34816   // 32768 assignments + up to 8*255 pad (x256 padding)
#define GIN    1792    // TD + ID_

typedef __bf16 bf16;
typedef __bf16 bf16x4 __attribute__((ext_vector_type(4)));
typedef __bf16 bf16x8 __attribute__((ext_vector_type(8)));
typedef float  f32x4  __attribute__((ext_vector_type(4)));

struct Top2 { int e0, e1; float w0, w1; };
struct Slot2 { int p0, p1; };

__device__ __forceinline__ void gload16(void* lds, const void* g) {
#if __has_builtin(__builtin_amdgcn_global_load_lds)
  __builtin_amdgcn_global_load_lds(
      (const __attribute__((address_space(1))) void*)g,
      (__attribute__((address_space(3))) void*)lds, 16, 0, 0);
#else
  *(int4*)lds = *(const int4*)g;   // reg-staged fallback
#endif
}

// ---------------- transpose + f32->bf16 convert: src[R][C] f32 -> dst[C][R] bf16
__global__ void transpose_cvt(const float* __restrict__ src, bf16* __restrict__ dst,
                              int R, int C) {
  src += (size_t)blockIdx.z * R * C;
  dst += (size_t)blockIdx.z * R * C;
  __shared__ float tile[64][65];
  const int r0 = blockIdx.y * 64, c0 = blockIdx.x * 64;
  const int t = threadIdx.x;
#pragma unroll
  for (int i = 0; i < 16; ++i) {
    int e = i * 256 + t;
    int ii = e >> 6, jj = e & 63;
    tile[ii][jj] = src[(size_t)(r0 + ii) * C + (c0 + jj)];
  }
  __syncthreads();
#pragma unroll
  for (int i = 0; i < 16; ++i) {
    int e = i * 256 + t;
    int ii = e >> 6, jj = e & 63;
    dst[(size_t)(c0 + ii) * R + (r0 + jj)] = (bf16)tile[jj][ii];
  }
}

// ---------------- fused gating matrices in fp64, TRANSPOSED output [e][1792]
__global__ void fuse_w(const float* __restrict__ Wt, const float* __restrict__ Wi,
                       const float* __restrict__ Wg, const float* __restrict__ bt,
                       const float* __restrict__ bi, const float* __restrict__ bg,
                       double* __restrict__ WgF, double* __restrict__ bgd) {
  int o = blockIdx.x * blockDim.x + threadIdx.x;
  if (o >= (GIN + 1) * NE) return;
  int idx = o >> 3, e = o & 7;
  if (idx < TD) {
    double s = 0.0;
    for (int h = 0; h < HID; ++h)
      s += (double)Wt[(size_t)idx * HID + h] * (double)Wg[(size_t)h * NE + e];
    WgF[(size_t)e * GIN + idx] = s;
  } else if (idx < GIN) {
    int r = idx - TD;
    double s = 0.0;
    for (int h = 0; h < HID; ++h)
      s += (double)Wi[(size_t)r * HID + h] * (double)Wg[(size_t)(HID + h) * NE + e];
    WgF[(size_t)e * GIN + idx] = s;
  } else {
    double s = (double)bg[e];
    for (int h = 0; h < HID; ++h) {
      s += (double)bt[h] * (double)Wg[(size_t)h * NE + e];
      s += (double)bi[h] * (double)Wg[(size_t)(HID + h) * NE + e];
    }
    bgd[e] = s;
  }
}

// ---------------- routing pass 1: LDS-staged fp64 weights, 64 rows per block.
__global__ __launch_bounds__(1024)
void route1(const float* __restrict__ text, const float* __restrict__ image,
            const float* __restrict__ noise,
            const double* __restrict__ WgF, const double* __restrict__ bgd,
            bf16* __restrict__ text_b, bf16* __restrict__ image_b,
            Top2* __restrict__ top2, int* __restrict__ counts) {
  __shared__ double wg[NE * GIN];        // 112 KiB
  __shared__ int lcnt[NE];
  const int t = threadIdx.x;
  if (t < NE) lcnt[t] = 0;
  {
    const ulonglong2* src = (const ulonglong2*)WgF;
    ulonglong2* dst = (ulonglong2*)wg;
#pragma unroll
    for (int i = 0; i < (NE * GIN) / 2 / 1024; ++i)
      dst[i * 1024 + t] = src[i * 1024 + t];
  }
  __syncthreads();

  const int wave = t >> 6, lane = t & 63;
  const int row0 = blockIdx.x * 64;
#pragma unroll
  for (int rr = 0; rr < 4; ++rr) {
    const int row = row0 + wave + rr * 16;
    const float* tr = text + (size_t)row * TD;
    const float* ir = image + (size_t)row * ID_;
    float xv[28];
#pragma unroll
    for (int c = 0; c < 12; ++c) xv[c] = tr[lane + 64 * c];
#pragma unroll
    for (int c = 0; c < 16; ++c) xv[12 + c] = ir[lane + 64 * c];
    bf16* tb = text_b + (size_t)row * TD;
    bf16* ib = image_b + (size_t)row * ID_;
#pragma unroll
    for (int c = 0; c < 12; ++c) tb[lane + 64 * c] = (bf16)xv[c];
#pragma unroll
    for (int c = 0; c < 16; ++c) ib[lane + 64 * c] = (bf16)xv[12 + c];

    double acc[NE];
#pragma unroll
    for (int e = 0; e < NE; ++e) acc[e] = 0.0;
#pragma unroll
    for (int c = 0; c < 28; ++c) {
      const double vd = (double)xv[c];
      const int idx = lane + 64 * c;
#pragma unroll
      for (int e = 0; e < NE; ++e) acc[e] = fma(vd, wg[e * GIN + idx], acc[e]);
    }
#pragma unroll
    for (int off = 32; off > 0; off >>= 1) {
#pragma unroll
      for (int e = 0; e < NE; ++e) acc[e] += __shfl_down(acc[e], off);
    }
    if (lane == 0) {
      float nz[NE];
#pragma unroll
      for (int e = 0; e < NE; ++e)
        nz[e] = (float)(acc[e] + bgd[e]) + noise[(size_t)row * NE + e];
      int i0 = 0;
#pragma unroll
      for (int e = 1; e < NE; ++e) if (nz[e] > nz[i0]) i0 = e;
      int i1 = (i0 == 0) ? 1 : 0;
#pragma unroll
      for (int e = 0; e < NE; ++e) if (e != i0 && nz[e] > nz[i1]) i1 = e;
      float tt = expf(nz[i1] - nz[i0]);
      float w0 = 1.0f / (1.0f + tt);
      float w1 = tt / (1.0f + tt);
      Top2 rec; rec.e0 = i0; rec.e1 = i1; rec.w0 = w0; rec.w1 = w1;
      top2[row] = rec;
      atomicAdd(&lcnt[i0], 1);
      atomicAdd(&lcnt[i1], 1);
    }
  }
  __syncthreads();
  if (t < NE) atomicAdd(&counts[t], lcnt[t]);
}

// ---------------- scan: offsets (padded to x256), init pos
__global__ void scan_pad(const int* __restrict__ counts, int* __restrict__ offsets,
                         int* __restrict__ padded, int* __restrict__ pos,
                         int* __restrict__ rows_list, float* __restrict__ wgt_list) {
  __shared__ int s_off[NE], s_cnt[NE], s_pad[NE];
  if (threadIdx.x == 0) {
    int off = 0;
    for (int e = 0; e < NE; ++e) {
      int c = counts[e];
      int pd = (c + 255) & ~255;
      s_cnt[e] = c; s_pad[e] = pd; s_off[e] = off;
      offsets[e] = off; padded[e] = pd; pos[e] = off;
      off += pd;
    }
    offsets[NE] = off;
  }
  __syncthreads();
  for (int e = 0; e < NE; ++e) {
    for (int i = s_cnt[e] + threadIdx.x; i < s_pad[e]; i += blockDim.x) {
      rows_list[s_off[e] + i] = 0;
      wgt_list[s_off[e] + i] = 0.0f;
    }
  }
}

// ---------------- routing pass 2: block-aggregated scatter + slot map
__global__ void route2(const Top2* __restrict__ top2, int* __restrict__ pos,
                       int* __restrict__ rows_list, float* __restrict__ wgt_list,
                       Slot2* __restrict__ slots) {
  __shared__ int lcnt[NE], lbase[NE];
  if (threadIdx.x < NE) lcnt[threadIdx.x] = 0;
  __syncthreads();
  const int r = blockIdx.x * 256 + threadIdx.x;
  Top2 tt = top2[r];
  int s0 = atomicAdd(&lcnt[tt.e0], 1);
  int s1 = atomicAdd(&lcnt[tt.e1], 1);
  __syncthreads();
  if (threadIdx.x < NE)
    lbase[threadIdx.x] = atomicAdd(&pos[threadIdx.x], lcnt[threadIdx.x]);
  __syncthreads();
  int p0 = lbase[tt.e0] + s0;
  rows_list[p0] = r; wgt_list[p0] = tt.w0;
  int p1 = lbase[tt.e1] + s1;
  rows_list[p1] = r; wgt_list[p1] = tt.w1;
  Slot2 sl; sl.p0 = p0; sl.p1 = p1;
  slots[r] = sl;
}

// ---------------- final combine: out[row] = pair[p0] + pair[p1]
__global__ __launch_bounds__(256)
void combine(const bf16* __restrict__ pairb, const Slot2* __restrict__ slots,
             float* __restrict__ out) {
  const int row = blockIdx.x;
  const Slot2 s = slots[row];
  const int t = threadIdx.x;
  const bf16x4 a = *(const bf16x4*)(pairb + (size_t)s.p0 * OD + t * 4);
  const bf16x4 b = *(const bf16x4*)(pairb + (size_t)s.p1 * OD + t * 4);
  f32x4 r;
#pragma unroll
  for (int j = 0; j < 4; ++j) r[j] = (float)a[j] + (float)b[j];
  *(f32x4*)(out + (size_t)row * OD + t * 4) = r;
}

// ============ 256x128 BK=32 triple-buffered bf16 MFMA GEMM, 2 blocks/CU ==========
// C[256x128 tile] = A[M][K] * BT[N][K]^T.  256 threads = 4 waves (2M x 2N),
// per-wave 128x64 output (acc[8][4]) -> 42.7 FLOP per LDS-read byte (was 32):
// round-8 showed runtime == LDS-read-bytes / 128 B/cy, so intensity is the lever.
// LDS 72 KiB: A[3][256][32], B[3][128][32]; 2-tile-deep prefetch, vmcnt(12)
// (6 loads/tile; stage kt+2 into buf[(kt+2)%3] = buffer last read at kt-1).
// 1D grid XCD decode (8 nblk, 64 mblk): xcd=bid&7; s=bid>>3; nblk=s&7;
// mblk=(s>>3)*8+xcd  -> A-tile's 8 N-blocks on one XCD (round-8 proven).
// Swizzle s(row)=(row>>1)&3 at source + read (round-8 proven, 0 conflicts).
// MODE 0: proj -> combined (bf16, +bias)
// MODE 1: expert FFN1 (gathered A rows) -> h (bf16, +b1, relu)
// MODE 2: expert FFN2 -> pairbuf (bf16, w*(acc+b2))

#define BARe  do { __builtin_amdgcn_s_barrier(); __builtin_amdgcn_sched_barrier(0); } while (0)
#define LGKM0 do { asm volatile("s_waitcnt lgkmcnt(0)" ::: "memory"); \
                   __builtin_amdgcn_sched_barrier(0); } while (0)
#define VMC12 asm volatile("s_waitcnt vmcnt(12)" ::: "memory")
#define PRIO1 __builtin_amdgcn_s_setprio(1)
#define PRIO0 __builtin_amdgcn_s_setprio(0)

#define STAGE_AB(BUF, KT) do { \
  _Pragma("unroll") for (int j_ = 0; j_ < 4; ++j_) \
    gload16(&As[BUF][aldso[j_]], aptr[j_] + (size_t)(KT) * 32); \
  _Pragma("unroll") for (int j_ = 0; j_ < 2; ++j_) \
    gload16(&Bs[BUF][bldso[j_]], bptr[j_] + (size_t)(KT) * 32); \
} while (0)

template<int MODE>
__global__ __launch_bounds__(256, 2)
void gemm256x128(const bf16* __restrict__ A, const bf16* __restrict__ BT,
                 const float* __restrict__ bias, bf16* __restrict__ outb,
                 const int* __restrict__ rows_list, const float* __restrict__ wgt_list,
                 const int* __restrict__ offsets, const int* __restrict__ padded,
                 int K, int lda, int ldb, int ldout, int coloff) {
  __shared__ bf16 As[3][256 * 32];   // 48 KiB
  __shared__ bf16 Bs[3][128 * 32];   // 24 KiB
  const int t = threadIdx.x;
  const int lane = t & 63, w = t >> 6;
  const int wm = w >> 1, wn = w & 1;
  // XCD-aware decode (8 N-tiles, 64 M-tiles in every GEMM here)
  const int bid = blockIdx.x;
  const int xcd = bid & 7, sdec = bid >> 3;
  const int nblk = sdec & 7, mblk = (sdec >> 3) * 8 + xcd;

  long base = 0;
  if constexpr (MODE != 0) {
    const int e = blockIdx.z;
    if (mblk * 256 >= padded[e]) return;
    base = offsets[e];
    if constexpr (MODE == 1) { BT += (size_t)e * HID * CB; bias += e * HID; }
    else                     { BT += (size_t)e * OD * HID; bias += e * OD; }
  }

  // staging: granule g covers row g>>2, granule slot g&3; LDS dest linear g*16B;
  // global source col pre-swizzled: logical gcol = (g&3) ^ ((row>>1)&3)
  const bf16* aptr[4]; int aldso[4];
#pragma unroll
  for (int j = 0; j < 4; ++j) {
    const int g = j * 256 + t, row = g >> 2;
    const int scol = ((g & 3) ^ ((row >> 1) & 3)) * 8;
    long ga;
    if constexpr (MODE == 1)      ga = rows_list[base + (long)mblk * 256 + row];
    else if constexpr (MODE == 2) ga = base + (long)mblk * 256 + row;
    else                          ga = (long)mblk * 256 + row;
    aptr[j] = A + ga * lda + scol;
    aldso[j] = g * 8;
  }
  const bf16* bptr[2]; int bldso[2];
#pragma unroll
  for (int j = 0; j < 2; ++j) {
    const int g = j * 256 + t, row = g >> 2;
    const int scol = ((g & 3) ^ ((row >> 1) & 3)) * 8;
    bptr[j] = BT + (size_t)(nblk * 128 + row) * ldb + scol;
    bldso[j] = g * 8;
  }

  // fragment reads: row = base16 + fr -> (row>>1)&3 = (fr>>1)&3
  const int fr = lane & 15;
  const int swz = ((lane >> 4) ^ ((fr >> 1) & 3)) * 8;
  int a_off[8], b_off[4];
#pragma unroll
  for (int f = 0; f < 8; ++f) a_off[f] = (wm * 128 + f * 16 + fr) * 32 + swz;
#pragma unroll
  for (int f = 0; f < 4; ++f) b_off[f] = (wn * 64 + f * 16 + fr) * 32 + swz;

  f32x4 acc[8][4];
#pragma unroll
  for (int i = 0; i < 8; ++i)
#pragma unroll
    for (int j = 0; j < 4; ++j)
#pragma unroll
      for (int r = 0; r < 4; ++r) acc[i][j][r] = 0.0f;

  const int NKT = K >> 5;

  STAGE_AB(0, 0);                  // tile 0 (6 loads)
  STAGE_AB(1, 1);                  // tile 1 (12 in flight)
  int cur = 0;
  for (int kt = 0; kt < NKT; ++kt) {
    const int kn = (kt + 2 < NKT) ? kt + 2 : 0;   // dummy at tail (never read)
    int sn = cur + 2; if (sn >= 3) sn -= 3;
    BARe;                          // prev iter's reads of buf[sn] complete
    STAGE_AB(sn, kn);              // 6 loads for tile kt+2
    VMC12;                         // <=12 outstanding => tile kt's 6 landed
    BARe;                          // tile kt visible to all waves
    bf16x8 af[8], bfr[4];
#pragma unroll
    for (int f = 0; f < 8; ++f) af[f]  = *(const bf16x8*)(&As[cur][a_off[f]]);
#pragma unroll
    for (int f = 0; f < 4; ++f) bfr[f] = *(const bf16x8*)(&Bs[cur][b_off[f]]);
    LGKM0;
    PRIO1;
#pragma unroll
    for (int mf = 0; mf < 8; ++mf)
#pragma unroll
      for (int nf = 0; nf < 4; ++nf)
        acc[mf][nf] = __builtin_amdgcn_mfma_f32_16x16x32_bf16(af[mf], bfr[nf],
                                                              acc[mf][nf], 0, 0, 0);
    PRIO0;
    cur = (cur + 1 < 3) ? cur + 1 : 0;
  }

  // epilogue: D row = (lane>>4)*4 + r, col = lane&15
  const int row_h = (lane >> 4) * 4;
#pragma unroll
  for (int nf = 0; nf < 4; ++nf) {
    const int gcol = nblk * 128 + wn * 64 + nf * 16 + fr;
    const float bv = bias[gcol];
#pragma unroll
    for (int mf = 0; mf < 8; ++mf) {
      const int rbase = wm * 128 + mf * 16 + row_h;
#pragma unroll
      for (int r = 0; r < 4; ++r) {
        const int rit = rbase + r;
        float v = acc[mf][nf][r] + bv;
        if constexpr (MODE == 0) {
          outb[((size_t)mblk * 256 + rit) * ldout + coloff + gcol] = (bf16)v;
        } else if constexpr (MODE == 1) {
          outb[(size_t)(base + (long)mblk * 256 + rit) * ldout + gcol] =
              (bf16)fmaxf(v, 0.0f);
        } else {
          const long li = base + (long)mblk * 256 + rit;
          const float wgt = wgt_list[li];
          outb[(size_t)li * ldout + gcol] = (bf16)(wgt * v);
        }
      }
    }
  }
}

extern "C" void kernel_launch(void* const* d_in, const int* in_sizes, int n_in,
                              void* d_out, int out_size, void* d_ws, size_t ws_size,
                              hipStream_t stream) {
  const float* text  = (const float*)d_in[0];
  const float* image = (const float*)d_in[1];
  const float* noise = (const float*)d_in[2];
  const float* Wt    = (const float*)d_in[3];
  const float* bt    = (const float*)d_in[4];
  const float* Wi    = (const float*)d_in[5];
  const float* bi    = (const float*)d_in[6];
  const float* Wg    = (const float*)d_in[7];
  const float* bg    = (const float*)d_in[8];
  const float* W1    = (const float*)d_in[9];
  const float* b1    = (const float*)d_in[10];
  const float* W2    = (const float*)d_in[11];
  const float* b2    = (const float*)d_in[12];
  float* out = (float*)d_out;

  char* p = (char*)d_ws;
  auto alloc = [&](size_t bytes) {
    char* r = p; p += (bytes + 255) & ~(size_t)255; return r;
  };
  // union region: {text_b, image_b} (early) / pairbuf (late, after proj GEMMs)
  const size_t sz_text  = (size_t)BB * TD * 2;
  const size_t sz_texta = (sz_text + 255) & ~(size_t)255;
  const size_t sz_image = (size_t)BB * ID_ * 2;
  const size_t sz_pair  = (size_t)CAPT * OD * 2;
  size_t sz_u0 = sz_texta + sz_image;
  if (sz_pair > sz_u0) sz_u0 = sz_pair;
  char* u0 = alloc(sz_u0);
  bf16* text_b  = (bf16*)u0;
  bf16* image_b = (bf16*)(u0 + sz_texta);
  bf16* pairb   = (bf16*)u0;

  bf16*   WtT      = (bf16*)alloc((size_t)HID * TD * 2);
  bf16*   WiT      = (bf16*)alloc((size_t)HID * ID_ * 2);
  bf16*   W1T      = (bf16*)alloc((size_t)NE * HID * CB * 2);
  bf16*   W2T      = (bf16*)alloc((size_t)NE * OD * HID * 2);
  bf16*   combined = (bf16*)alloc((size_t)BB * CB * 2);
  bf16*   hbuf     = (bf16*)alloc((size_t)CAPT * HID * 2);
  double* WgF      = (double*)alloc((size_t)NE * GIN * 8);
  double* bgd      = (double*)alloc((size_t)NE * 8);
  Top2*   top2     = (Top2*)alloc((size_t)BB * sizeof(Top2));
  Slot2*  slots    = (Slot2*)alloc((size_t)BB * sizeof(Slot2));
  int*    counts   = (int*)alloc(NE * 4);
  int*    offsets  = (int*)alloc((NE + 1) * 4);
  int*    padded   = (int*)alloc(NE * 4);
  int*    pos      = (int*)alloc(NE * 4);
  int*    rows_list= (int*)alloc((size_t)CAPT * 4);
  float*  wgt_list = (float*)alloc((size_t)CAPT * 4);

  hipMemsetAsync(counts, 0, NE * 4, stream);

  transpose_cvt<<<dim3(HID / 64, TD / 64, 1),  256, 0, stream>>>(Wt, WtT, TD, HID);
  transpose_cvt<<<dim3(HID / 64, ID_ / 64, 1), 256, 0, stream>>>(Wi, WiT, ID_, HID);
  transpose_cvt<<<dim3(HID / 64, CB / 64, NE), 256, 0, stream>>>(W1, W1T, CB, HID);
  transpose_cvt<<<dim3(OD / 64, HID / 64, NE), 256, 0, stream>>>(W2, W2T, HID, OD);

  fuse_w<<<((GIN + 1) * NE + 255) / 256, 256, 0, stream>>>(
      Wt, Wi, Wg, bt, bi, bg, WgF, bgd);
  route1<<<BB / 64, 1024, 0, stream>>>(text, image, noise, WgF, bgd,
                                       text_b, image_b, top2, counts);
  scan_pad<<<1, 256, 0, stream>>>(counts, offsets, padded, pos, rows_list, wgt_list);
  route2<<<BB / 256, 256, 0, stream>>>(top2, pos, rows_list, wgt_list, slots);

  // proj: combined[:, :1024] = text @ Wt + bt ; combined[:, 1024:] = image @ Wi + bi
  // 1D grid: 64 mblk x 8 nblk = 512 blocks, XCD-decoded in-kernel
  gemm256x128<0><<<dim3(512, 1, 1), 256, 0, stream>>>(
      text_b, WtT, bt, combined, nullptr, nullptr, nullptr, nullptr,
      TD, TD, TD, CB, 0);
  gemm256x128<0><<<dim3(512, 1, 1), 256, 0, stream>>>(
      image_b, WiT, bi, combined, nullptr, nullptr, nullptr, nullptr,
      ID_, ID_, ID_, CB, HID);
  // expert FFN1 (gathered) -> h   (64 mblk covers worst-case 16384 rows/expert)
  gemm256x128<1><<<dim3(512, 1, NE), 256, 0, stream>>>(
      combined, W1T, b1, hbuf, rows_list, nullptr, offsets, padded,
      CB, CB, CB, HID, 0);
  // expert FFN2 -> pair buffer (plain bf16 stores)
  gemm256x128<2><<<dim3(512, 1, NE), 256, 0, stream>>>(
      hbuf, W2T, b2, pairb, rows_list, wgt_list, offsets, padded,
      HID, HID, HID, OD, 0);
  // final: out[row] = pair[p0] + pair[p1]
  combine<<<BB, 256, 0, stream>>>(pairb, slots, out);
}

// Round 10
// 575.798 us; speedup vs baseline: 1.1300x; 1.1300x over previous
//
#include <hip/hip_runtime.h>
#include <stdint.h>
#include <stddef.h>

#define BB     16384
#define TD     768
#define ID_    1024
#define HID    1024
#define OD     1024
#define NE     8
#define CB     2048
#define CAPT   33792   // 32768 assignments + up to 8*127 pad (x128 padding)
#define GIN    1792    // TD + ID_

typedef __bf16 bf16;
typedef __bf16 bf16x4 __attribute__((ext_vector_type(4)));
typedef __bf16 bf16x8 __attribute__((ext_vector_type(8)));
typedef float  f32x4  __attribute__((ext_vector_type(4)));

struct Top2 { int e0, e1; float w0, w1; };
struct Slot2 { int p0, p1; };

__device__ __forceinline__ void gload16(void* lds, const void* g) {
#if __has_builtin(__builtin_amdgcn_global_load_lds)
  __builtin_amdgcn_global_load_lds(
      (const __attribute__((address_space(1))) void*)g,
      (__attribute__((address_space(3))) void*)lds, 16, 0, 0);
#else
  *(int4*)lds = *(const int4*)g;   // reg-staged fallback
#endif
}

// ---------------- transpose + f32->bf16 convert: src[R][C] f32 -> dst[C][R] bf16
__global__ void transpose_cvt(const float* __restrict__ src, bf16* __restrict__ dst,
                              int R, int C) {
  src += (size_t)blockIdx.z * R * C;
  dst += (size_t)blockIdx.z * R * C;
  __shared__ float tile[64][65];
  const int r0 = blockIdx.y * 64, c0 = blockIdx.x * 64;
  const int t = threadIdx.x;
#pragma unroll
  for (int i = 0; i < 16; ++i) {
    int e = i * 256 + t;
    int ii = e >> 6, jj = e & 63;
    tile[ii][jj] = src[(size_t)(r0 + ii) * C + (c0 + jj)];
  }
  __syncthreads();
#pragma unroll
  for (int i = 0; i < 16; ++i) {
    int e = i * 256 + t;
    int ii = e >> 6, jj = e & 63;
    dst[(size_t)(c0 + ii) * R + (r0 + jj)] = (bf16)tile[jj][ii];
  }
}

// ---------------- fused gating matrices in fp64, TRANSPOSED output [e][1792]
__global__ void fuse_w(const float* __restrict__ Wt, const float* __restrict__ Wi,
                       const float* __restrict__ Wg, const float* __restrict__ bt,
                       const float* __restrict__ bi, const float* __restrict__ bg,
                       double* __restrict__ WgF, double* __restrict__ bgd) {
  int o = blockIdx.x * blockDim.x + threadIdx.x;
  if (o >= (GIN + 1) * NE) return;
  int idx = o >> 3, e = o & 7;
  if (idx < TD) {
    double s = 0.0;
    for (int h = 0; h < HID; ++h)
      s += (double)Wt[(size_t)idx * HID + h] * (double)Wg[(size_t)h * NE + e];
    WgF[(size_t)e * GIN + idx] = s;
  } else if (idx < GIN) {
    int r = idx - TD;
    double s = 0.0;
    for (int h = 0; h < HID; ++h)
      s += (double)Wi[(size_t)r * HID + h] * (double)Wg[(size_t)(HID + h) * NE + e];
    WgF[(size_t)e * GIN + idx] = s;
  } else {
    double s = (double)bg[e];
    for (int h = 0; h < HID; ++h) {
      s += (double)bt[h] * (double)Wg[(size_t)h * NE + e];
      s += (double)bi[h] * (double)Wg[(size_t)(HID + h) * NE + e];
    }
    bgd[e] = s;
  }
}

// ---------------- routing pass 1: LDS-staged fp64 weights, 64 rows per block.
__global__ __launch_bounds__(1024)
void route1(const float* __restrict__ text, const float* __restrict__ image,
            const float* __restrict__ noise,
            const double* __restrict__ WgF, const double* __restrict__ bgd,
            bf16* __restrict__ text_b, bf16* __restrict__ image_b,
            Top2* __restrict__ top2, int* __restrict__ counts) {
  __shared__ double wg[NE * GIN];        // 112 KiB
  __shared__ int lcnt[NE];
  const int t = threadIdx.x;
  if (t < NE) lcnt[t] = 0;
  {
    const ulonglong2* src = (const ulonglong2*)WgF;
    ulonglong2* dst = (ulonglong2*)wg;
#pragma unroll
    for (int i = 0; i < (NE * GIN) / 2 / 1024; ++i)
      dst[i * 1024 + t] = src[i * 1024 + t];
  }
  __syncthreads();

  const int wave = t >> 6, lane = t & 63;
  const int row0 = blockIdx.x * 64;
#pragma unroll
  for (int rr = 0; rr < 4; ++rr) {
    const int row = row0 + wave + rr * 16;
    const float* tr = text + (size_t)row * TD;
    const float* ir = image + (size_t)row * ID_;
    float xv[28];
#pragma unroll
    for (int c = 0; c < 12; ++c) xv[c] = tr[lane + 64 * c];
#pragma unroll
    for (int c = 0; c < 16; ++c) xv[12 + c] = ir[lane + 64 * c];
    bf16* tb = text_b + (size_t)row * TD;
    bf16* ib = image_b + (size_t)row * ID_;
#pragma unroll
    for (int c = 0; c < 12; ++c) tb[lane + 64 * c] = (bf16)xv[c];
#pragma unroll
    for (int c = 0; c < 16; ++c) ib[lane + 64 * c] = (bf16)xv[12 + c];

    double acc[NE];
#pragma unroll
    for (int e = 0; e < NE; ++e) acc[e] = 0.0;
#pragma unroll
    for (int c = 0; c < 28; ++c) {
      const double vd = (double)xv[c];
      const int idx = lane + 64 * c;
#pragma unroll
      for (int e = 0; e < NE; ++e) acc[e] = fma(vd, wg[e * GIN + idx], acc[e]);
    }
#pragma unroll
    for (int off = 32; off > 0; off >>= 1) {
#pragma unroll
      for (int e = 0; e < NE; ++e) acc[e] += __shfl_down(acc[e], off);
    }
    if (lane == 0) {
      float nz[NE];
#pragma unroll
      for (int e = 0; e < NE; ++e)
        nz[e] = (float)(acc[e] + bgd[e]) + noise[(size_t)row * NE + e];
      int i0 = 0;
#pragma unroll
      for (int e = 1; e < NE; ++e) if (nz[e] > nz[i0]) i0 = e;
      int i1 = (i0 == 0) ? 1 : 0;
#pragma unroll
      for (int e = 0; e < NE; ++e) if (e != i0 && nz[e] > nz[i1]) i1 = e;
      float tt = expf(nz[i1] - nz[i0]);
      float w0 = 1.0f / (1.0f + tt);
      float w1 = tt / (1.0f + tt);
      Top2 rec; rec.e0 = i0; rec.e1 = i1; rec.w0 = w0; rec.w1 = w1;
      top2[row] = rec;
      atomicAdd(&lcnt[i0], 1);
      atomicAdd(&lcnt[i1], 1);
    }
  }
  __syncthreads();
  if (t < NE) atomicAdd(&counts[t], lcnt[t]);
}

// ---------------- scan: offsets (padded to x128), init pos
__global__ void scan_pad(const int* __restrict__ counts, int* __restrict__ offsets,
                         int* __restrict__ padded, int* __restrict__ pos,
                         int* __restrict__ rows_list, float* __restrict__ wgt_list) {
  __shared__ int s_off[NE], s_cnt[NE], s_pad[NE];
  if (threadIdx.x == 0) {
    int off = 0;
    for (int e = 0; e < NE; ++e) {
      int c = counts[e];
      int pd = (c + 127) & ~127;
      s_cnt[e] = c; s_pad[e] = pd; s_off[e] = off;
      offsets[e] = off; padded[e] = pd; pos[e] = off;
      off += pd;
    }
    offsets[NE] = off;
  }
  __syncthreads();
  for (int e = 0; e < NE; ++e) {
    for (int i = s_cnt[e] + threadIdx.x; i < s_pad[e]; i += blockDim.x) {
      rows_list[s_off[e] + i] = 0;
      wgt_list[s_off[e] + i] = 0.0f;
    }
  }
}

// ---------------- routing pass 2: block-aggregated scatter + slot map
__global__ void route2(const Top2* __restrict__ top2, int* __restrict__ pos,
                       int* __restrict__ rows_list, float* __restrict__ wgt_list,
                       Slot2* __restrict__ slots) {
  __shared__ int lcnt[NE], lbase[NE];
  if (threadIdx.x < NE) lcnt[threadIdx.x] = 0;
  __syncthreads();
  const int r = blockIdx.x * 256 + threadIdx.x;
  Top2 tt = top2[r];
  int s0 = atomicAdd(&lcnt[tt.e0], 1);
  int s1 = atomicAdd(&lcnt[tt.e1], 1);
  __syncthreads();
  if (threadIdx.x < NE)
    lbase[threadIdx.x] = atomicAdd(&pos[threadIdx.x], lcnt[threadIdx.x]);
  __syncthreads();
  int p0 = lbase[tt.e0] + s0;
  rows_list[p0] = r; wgt_list[p0] = tt.w0;
  int p1 = lbase[tt.e1] + s1;
  rows_list[p1] = r; wgt_list[p1] = tt.w1;
  Slot2 sl; sl.p0 = p0; sl.p1 = p1;
  slots[r] = sl;
}

// ---------------- final combine: out[row] = pair[p0] + pair[p1]
__global__ __launch_bounds__(256)
void combine(const bf16* __restrict__ pairb, const Slot2* __restrict__ slots,
             float* __restrict__ out) {
  const int row = blockIdx.x;
  const Slot2 s = slots[row];
  const int t = threadIdx.x;
  const bf16x4 a = *(const bf16x4*)(pairb + (size_t)s.p0 * OD + t * 4);
  const bf16x4 b = *(const bf16x4*)(pairb + (size_t)s.p1 * OD + t * 4);
  f32x4 r;
#pragma unroll
  for (int j = 0; j < 4; ++j) r[j] = (float)a[j] + (float)b[j];
  *(f32x4*)(out + (size_t)row * OD + t * 4) = r;
}

// ========== 128x128 BK=32 TRIPLE-buffered (2-deep prefetch), 3 blocks/CU ==========
// Round-8 base (best: 574 us total) + two changes:
//  (1) prefetch depth 2: third LDS buffer (48 KiB -> 3 blocks/CU vs r8's 4);
//      current tile's loads get ~2 iterations in flight before vmcnt needs them.
//  (2) no forced lgkmcnt(0) drain before MFMA: compiler emits fine-grained
//      lgkmcnt(N) per fragment use -> early MFMAs overlap late ds_reads.
// Everything else r8-proven: swizzle s(row)=(row>>1)&3 (0 conflicts), 1D grid
// XCD decode (A-tile's 8 N-blocks on one XCD), x128 expert padding.
// MODE 0: proj -> combined (bf16, +bias)
// MODE 1: expert FFN1 (gathered A rows) -> h (bf16, +b1, relu)
// MODE 2: expert FFN2 -> pairbuf (bf16, w*(acc+b2))

#define BARe  do { __builtin_amdgcn_s_barrier(); __builtin_amdgcn_sched_barrier(0); } while (0)
#define VMC8  asm volatile("s_waitcnt vmcnt(8)" ::: "memory")
#define PRIO1 __builtin_amdgcn_s_setprio(1)
#define PRIO0 __builtin_amdgcn_s_setprio(0)

#define STAGE128(BUF, KT) do { \
  _Pragma("unroll") for (int j_ = 0; j_ < 2; ++j_) { \
    gload16(&As[BUF][ldsoff[j_]], aptr[j_] + (size_t)(KT) * 32); \
    gload16(&Bs[BUF][ldsoff[j_]], bptr[j_] + (size_t)(KT) * 32); \
  } \
} while (0)

template<int MODE>
__global__ __launch_bounds__(256, 3)
void gemm128(const bf16* __restrict__ A, const bf16* __restrict__ BT,
             const float* __restrict__ bias, bf16* __restrict__ outb,
             const int* __restrict__ rows_list, const float* __restrict__ wgt_list,
             const int* __restrict__ offsets, const int* __restrict__ padded,
             int K, int lda, int ldb, int ldout, int coloff) {
  __shared__ bf16 As[3][128 * 32];   // 24 KiB
  __shared__ bf16 Bs[3][128 * 32];   // 24 KiB
  const int t = threadIdx.x;
  const int lane = t & 63, w = t >> 6;
  const int wm = w >> 1, wn = w & 1;
  // XCD-aware decode (8 N-tiles in every GEMM here)
  const int bid = blockIdx.x;
  const int xcd = bid & 7, sdec = bid >> 3;
  const int nblk = sdec & 7, mblk = (sdec >> 3) * 8 + xcd;

  long base = 0;
  if constexpr (MODE != 0) {
    const int e = blockIdx.z;
    if (mblk * 128 >= padded[e]) return;
    base = offsets[e];
    if constexpr (MODE == 1) { BT += (size_t)e * HID * CB; bias += e * HID; }
    else                     { BT += (size_t)e * OD * HID; bias += e * OD; }
  }

  // staging: load j covers granule g=j*256+t; row=g>>2; LDS dest linear (g*16B);
  // global source col pre-swizzled: logical gcol = (g&3) ^ ((row>>1)&3)
  const bf16* aptr[2]; const bf16* bptr[2]; int ldsoff[2];
#pragma unroll
  for (int j = 0; j < 2; ++j) {
    const int g = j * 256 + t, row = g >> 2;
    const int scol = ((g & 3) ^ ((row >> 1) & 3)) * 8;
    long ga;
    if constexpr (MODE == 1)      ga = rows_list[base + (long)mblk * 128 + row];
    else if constexpr (MODE == 2) ga = base + (long)mblk * 128 + row;
    else                          ga = (long)mblk * 128 + row;
    aptr[j] = A + ga * lda + scol;
    bptr[j] = BT + (size_t)(nblk * 128 + row) * ldb + scol;
    ldsoff[j] = g * 8;
  }

  // fragment reads: row = base16 + fr (base16 % 16 == 0) -> (row>>1)&3 = (fr>>1)&3
  const int fr = lane & 15;
  const int swz = ((lane >> 4) ^ ((fr >> 1) & 3)) * 8;
  int a_off[4], b_off[4];
#pragma unroll
  for (int f = 0; f < 4; ++f) {
    a_off[f] = (wm * 64 + f * 16 + fr) * 32 + swz;
    b_off[f] = (wn * 64 + f * 16 + fr) * 32 + swz;
  }

  f32x4 acc[4][4];
#pragma unroll
  for (int i = 0; i < 4; ++i)
#pragma unroll
    for (int j = 0; j < 4; ++j)
#pragma unroll
      for (int r = 0; r < 4; ++r) acc[i][j][r] = 0.0f;

  const int NKT = K >> 5;

  STAGE128(0, 0);                       // tile 0 -> buf0 (4 loads)
  STAGE128(1, 1);                       // tile 1 -> buf1 (8 in flight)
  int cur = 0;
  for (int kt = 0; kt < NKT; ++kt) {
    const int kn = (kt + 2 < NKT) ? kt + 2 : 0;   // dummy at tail (never read)
    int sn = cur + 2; if (sn >= 3) sn -= 3;
    BARe;                               // buf[sn]'s last readers are past their MFMAs
    STAGE128(sn, kn);                   // 4 loads for tile kt+2 (12 outstanding)
    VMC8;                               // <=8 outstanding => tile kt's 4 landed
    BARe;                               // tile kt visible to all waves
    bf16x8 af[4], bfr[4];
#pragma unroll
    for (int f = 0; f < 4; ++f) af[f]  = *(const bf16x8*)(&As[cur][a_off[f]]);
#pragma unroll
    for (int f = 0; f < 4; ++f) bfr[f] = *(const bf16x8*)(&Bs[cur][b_off[f]]);
    // no forced lgkm drain: compiler inserts fine-grained lgkmcnt per use
    PRIO1;
#pragma unroll
    for (int mf = 0; mf < 4; ++mf)
#pragma unroll
      for (int nf = 0; nf < 4; ++nf)
        acc[mf][nf] = __builtin_amdgcn_mfma_f32_16x16x32_bf16(af[mf], bfr[nf],
                                                              acc[mf][nf], 0, 0, 0);
    PRIO0;
    cur = (cur + 1 < 3) ? cur + 1 : 0;
  }

  // epilogue: D row = (lane>>4)*4 + r, col = lane&15
  const int row_h = (lane >> 4) * 4;
#pragma unroll
  for (int nf = 0; nf < 4; ++nf) {
    const int gcol = nblk * 128 + wn * 64 + nf * 16 + fr;
    const float bv = bias[gcol];
#pragma unroll
    for (int mf = 0; mf < 4; ++mf) {
      const int rbase = wm * 64 + mf * 16 + row_h;
#pragma unroll
      for (int r = 0; r < 4; ++r) {
        const int rit = rbase + r;
        float v = acc[mf][nf][r] + bv;
        if constexpr (MODE == 0) {
          outb[((size_t)mblk * 128 + rit) * ldout + coloff + gcol] = (bf16)v;
        } else if constexpr (MODE == 1) {
          outb[(size_t)(base + (long)mblk * 128 + rit) * ldout + gcol] =
              (bf16)fmaxf(v, 0.0f);
        } else {
          const long li = base + (long)mblk * 128 + rit;
          const float wgt = wgt_list[li];
          outb[(size_t)li * ldout + gcol] = (bf16)(wgt * v);
        }
      }
    }
  }
}

extern "C" void kernel_launch(void* const* d_in, const int* in_sizes, int n_in,
                              void* d_out, int out_size, void* d_ws, size_t ws_size,
                              hipStream_t stream) {
  const float* text  = (const float*)d_in[0];
  const float* image = (const float*)d_in[1];
  const float* noise = (const float*)d_in[2];
  const float* Wt    = (const float*)d_in[3];
  const float* bt    = (const float*)d_in[4];
  const float* Wi    = (const float*)d_in[5];
  const float* bi    = (const float*)d_in[6];
  const float* Wg    = (const float*)d_in[7];
  const float* bg    = (const float*)d_in[8];
  const float* W1    = (const float*)d_in[9];
  const float* b1    = (const float*)d_in[10];
  const float* W2    = (const float*)d_in[11];
  const float* b2    = (const float*)d_in[12];
  float* out = (float*)d_out;

  char* p = (char*)d_ws;
  auto alloc = [&](size_t bytes) {
    char* r = p; p += (bytes + 255) & ~(size_t)255; return r;
  };
  // union region: {text_b, image_b} (early) / pairbuf (late, after proj GEMMs)
  const size_t sz_text  = (size_t)BB * TD * 2;
  const size_t sz_texta = (sz_text + 255) & ~(size_t)255;
  const size_t sz_image = (size_t)BB * ID_ * 2;
  const size_t sz_pair  = (size_t)CAPT * OD * 2;
  size_t sz_u0 = sz_texta + sz_image;
  if (sz_pair > sz_u0) sz_u0 = sz_pair;
  char* u0 = alloc(sz_u0);
  bf16* text_b  = (bf16*)u0;
  bf16* image_b = (bf16*)(u0 + sz_texta);
  bf16* pairb   = (bf16*)u0;

  bf16*   WtT      = (bf16*)alloc((size_t)HID * TD * 2);
  bf16*   WiT      = (bf16*)alloc((size_t)HID * ID_ * 2);
  bf16*   W1T      = (bf16*)alloc((size_t)NE * HID * CB * 2);
  bf16*   W2T      = (bf16*)alloc((size_t)NE * OD * HID * 2);
  bf16*   combined = (bf16*)alloc((size_t)BB * CB * 2);
  bf16*   hbuf     = (bf16*)alloc((size_t)CAPT * HID * 2);
  double* WgF      = (double*)alloc((size_t)NE * GIN * 8);
  double* bgd      = (double*)alloc((size_t)NE * 8);
  Top2*   top2     = (Top2*)alloc((size_t)BB * sizeof(Top2));
  Slot2*  slots    = (Slot2*)alloc((size_t)BB * sizeof(Slot2));
  int*    counts   = (int*)alloc(NE * 4);
  int*    offsets  = (int*)alloc((NE + 1) * 4);
  int*    padded   = (int*)alloc(NE * 4);
  int*    pos      = (int*)alloc(NE * 4);
  int*    rows_list= (int*)alloc((size_t)CAPT * 4);
  float*  wgt_list = (float*)alloc((size_t)CAPT * 4);

  hipMemsetAsync(counts, 0, NE * 4, stream);

  transpose_cvt<<<dim3(HID / 64, TD / 64, 1),  256, 0, stream>>>(Wt, WtT, TD, HID);
  transpose_cvt<<<dim3(HID / 64, ID_ / 64, 1), 256, 0, stream>>>(Wi, WiT, ID_, HID);
  transpose_cvt<<<dim3(HID / 64, CB / 64, NE), 256, 0, stream>>>(W1, W1T, CB, HID);
  transpose_cvt<<<dim3(OD / 64, HID / 64, NE), 256, 0, stream>>>(W2, W2T, HID, OD);

  fuse_w<<<((GIN + 1) * NE + 255) / 256, 256, 0, stream>>>(
      Wt, Wi, Wg, bt, bi, bg, WgF, bgd);
  route1<<<BB / 64, 1024, 0, stream>>>(text, image, noise, WgF, bgd,
                                       text_b, image_b, top2, counts);
  scan_pad<<<1, 256, 0, stream>>>(counts, offsets, padded, pos, rows_list, wgt_list);
  route2<<<BB / 256, 256, 0, stream>>>(top2, pos, rows_list, wgt_list, slots);

  // proj: combined[:, :1024] = text @ Wt + bt ; combined[:, 1024:] = image @ Wi + bi
  // 1D grid: 128 mblk x 8 nblk = 1024 blocks, XCD-decoded in-kernel
  gemm128<0><<<dim3(1024, 1, 1), 256, 0, stream>>>(
      text_b, WtT, bt, combined, nullptr, nullptr, nullptr, nullptr,
      TD, TD, TD, CB, 0);
  gemm128<0><<<dim3(1024, 1, 1), 256, 0, stream>>>(
      image_b, WiT, bi, combined, nullptr, nullptr, nullptr, nullptr,
      ID_, ID_, ID_, CB, HID);
  // expert FFN1 (gathered) -> h   (128 mblk covers worst-case 16384 rows/expert)
  gemm128<1><<<dim3(1024, 1, NE), 256, 0, stream>>>(
      combined, W1T, b1, hbuf, rows_list, nullptr, offsets, padded,
      CB, CB, CB, HID, 0);
  // expert FFN2 -> pair buffer (plain bf16 stores)
  gemm128<2><<<dim3(1024, 1, NE), 256, 0, stream>>>(
      hbuf, W2T, b2, pairb, rows_list, wgt_list, offsets, padded,
      HID, HID, HID, OD, 0);
  // final: out[row] = pair[p0] + pair[p1]
  combine<<<BB, 256, 0, stream>>>(pairb, slots, out);
}

// Round 11
// 528.676 us; speedup vs baseline: 1.2307x; 1.0891x over previous
//
#include <hip/hip_runtime.h>
#include <stdint.h>
#include <stddef.h>

#define BB     16384
#define TD     768
#define ID_    1024
#define HID    1024
#define OD     1024
#define NE     8
#define CB     2048
#define CAPT   33792   // 32768 assignments + up to 8*127 pad (x128 padding)
#define GIN    1792    // TD + ID_

typedef __bf16 bf16;
typedef __bf16 bf16x4 __attribute__((ext_vector_type(4)));
typedef __bf16 bf16x8 __attribute__((ext_vector_type(8)));
typedef float  f32x4  __attribute__((ext_vector_type(4)));

struct Top2 { int e0, e1; float w0, w1; };
struct Slot2 { int p0, p1; };

__device__ __forceinline__ void gload16(void* lds, const void* g) {
#if __has_builtin(__builtin_amdgcn_global_load_lds)
  __builtin_amdgcn_global_load_lds(
      (const __attribute__((address_space(1))) void*)g,
      (__attribute__((address_space(3))) void*)lds, 16, 0, 0);
#else
  *(int4*)lds = *(const int4*)g;   // reg-staged fallback
#endif
}

// ---------------- transpose + f32->bf16 convert: src[R][C] f32 -> dst[C][R] bf16
__global__ void transpose_cvt(const float* __restrict__ src, bf16* __restrict__ dst,
                              int R, int C) {
  src += (size_t)blockIdx.z * R * C;
  dst += (size_t)blockIdx.z * R * C;
  __shared__ float tile[64][65];
  const int r0 = blockIdx.y * 64, c0 = blockIdx.x * 64;
  const int t = threadIdx.x;
#pragma unroll
  for (int i = 0; i < 16; ++i) {
    int e = i * 256 + t;
    int ii = e >> 6, jj = e & 63;
    tile[ii][jj] = src[(size_t)(r0 + ii) * C + (c0 + jj)];
  }
  __syncthreads();
#pragma unroll
  for (int i = 0; i < 16; ++i) {
    int e = i * 256 + t;
    int ii = e >> 6, jj = e & 63;
    dst[(size_t)(c0 + ii) * R + (r0 + jj)] = (bf16)tile[jj][ii];
  }
}

// ---------------- fused gating matrices in fp64, TRANSPOSED output [e][1792]
__global__ void fuse_w(const float* __restrict__ Wt, const float* __restrict__ Wi,
                       const float* __restrict__ Wg, const float* __restrict__ bt,
                       const float* __restrict__ bi, const float* __restrict__ bg,
                       double* __restrict__ WgF, double* __restrict__ bgd) {
  int o = blockIdx.x * blockDim.x + threadIdx.x;
  if (o >= (GIN + 1) * NE) return;
  int idx = o >> 3, e = o & 7;
  if (idx < TD) {
    double s = 0.0;
    for (int h = 0; h < HID; ++h)
      s += (double)Wt[(size_t)idx * HID + h] * (double)Wg[(size_t)h * NE + e];
    WgF[(size_t)e * GIN + idx] = s;
  } else if (idx < GIN) {
    int r = idx - TD;
    double s = 0.0;
    for (int h = 0; h < HID; ++h)
      s += (double)Wi[(size_t)r * HID + h] * (double)Wg[(size_t)(HID + h) * NE + e];
    WgF[(size_t)e * GIN + idx] = s;
  } else {
    double s = (double)bg[e];
    for (int h = 0; h < HID; ++h) {
      s += (double)bt[h] * (double)Wg[(size_t)h * NE + e];
      s += (double)bi[h] * (double)Wg[(size_t)(HID + h) * NE + e];
    }
    bgd[e] = s;
  }
}

// ---------------- routing pass 1: LDS-staged fp64 weights, 64 rows per block.
__global__ __launch_bounds__(1024)
void route1(const float* __restrict__ text, const float* __restrict__ image,
            const float* __restrict__ noise,
            const double* __restrict__ WgF, const double* __restrict__ bgd,
            bf16* __restrict__ text_b, bf16* __restrict__ image_b,
            Top2* __restrict__ top2, int* __restrict__ counts) {
  __shared__ double wg[NE * GIN];        // 112 KiB
  __shared__ int lcnt[NE];
  const int t = threadIdx.x;
  if (t < NE) lcnt[t] = 0;
  {
    const ulonglong2* src = (const ulonglong2*)WgF;
    ulonglong2* dst = (ulonglong2*)wg;
#pragma unroll
    for (int i = 0; i < (NE * GIN) / 2 / 1024; ++i)
      dst[i * 1024 + t] = src[i * 1024 + t];
  }
  __syncthreads();

  const int wave = t >> 6, lane = t & 63;
  const int row0 = blockIdx.x * 64;
#pragma unroll
  for (int rr = 0; rr < 4; ++rr) {
    const int row = row0 + wave + rr * 16;
    const float* tr = text + (size_t)row * TD;
    const float* ir = image + (size_t)row * ID_;
    float xv[28];
#pragma unroll
    for (int c = 0; c < 12; ++c) xv[c] = tr[lane + 64 * c];
#pragma unroll
    for (int c = 0; c < 16; ++c) xv[12 + c] = ir[lane + 64 * c];
    bf16* tb = text_b + (size_t)row * TD;
    bf16* ib = image_b + (size_t)row * ID_;
#pragma unroll
    for (int c = 0; c < 12; ++c) tb[lane + 64 * c] = (bf16)xv[c];
#pragma unroll
    for (int c = 0; c < 16; ++c) ib[lane + 64 * c] = (bf16)xv[12 + c];

    double acc[NE];
#pragma unroll
    for (int e = 0; e < NE; ++e) acc[e] = 0.0;
#pragma unroll
    for (int c = 0; c < 28; ++c) {
      const double vd = (double)xv[c];
      const int idx = lane + 64 * c;
#pragma unroll
      for (int e = 0; e < NE; ++e) acc[e] = fma(vd, wg[e * GIN + idx], acc[e]);
    }
#pragma unroll
    for (int off = 32; off > 0; off >>= 1) {
#pragma unroll
      for (int e = 0; e < NE; ++e) acc[e] += __shfl_down(acc[e], off);
    }
    if (lane == 0) {
      float nz[NE];
#pragma unroll
      for (int e = 0; e < NE; ++e)
        nz[e] = (float)(acc[e] + bgd[e]) + noise[(size_t)row * NE + e];
      int i0 = 0;
#pragma unroll
      for (int e = 1; e < NE; ++e) if (nz[e] > nz[i0]) i0 = e;
      int i1 = (i0 == 0) ? 1 : 0;
#pragma unroll
      for (int e = 0; e < NE; ++e) if (e != i0 && nz[e] > nz[i1]) i1 = e;
      float tt = expf(nz[i1] - nz[i0]);
      float w0 = 1.0f / (1.0f + tt);
      float w1 = tt / (1.0f + tt);
      Top2 rec; rec.e0 = i0; rec.e1 = i1; rec.w0 = w0; rec.w1 = w1;
      top2[row] = rec;
      atomicAdd(&lcnt[i0], 1);
      atomicAdd(&lcnt[i1], 1);
    }
  }
  __syncthreads();
  if (t < NE) atomicAdd(&counts[t], lcnt[t]);
}

// ---------------- scan: offsets (padded to x128), init pos
__global__ void scan_pad(const int* __restrict__ counts, int* __restrict__ offsets,
                         int* __restrict__ padded, int* __restrict__ pos,
                         int* __restrict__ rows_list, float* __restrict__ wgt_list) {
  __shared__ int s_off[NE], s_cnt[NE], s_pad[NE];
  if (threadIdx.x == 0) {
    int off = 0;
    for (int e = 0; e < NE; ++e) {
      int c = counts[e];
      int pd = (c + 127) & ~127;
      s_cnt[e] = c; s_pad[e] = pd; s_off[e] = off;
      offsets[e] = off; padded[e] = pd; pos[e] = off;
      off += pd;
    }
    offsets[NE] = off;
  }
  __syncthreads();
  for (int e = 0; e < NE; ++e) {
    for (int i = s_cnt[e] + threadIdx.x; i < s_pad[e]; i += blockDim.x) {
      rows_list[s_off[e] + i] = 0;
      wgt_list[s_off[e] + i] = 0.0f;
    }
  }
}

// ---------------- routing pass 2: block-aggregated scatter + slot map
__global__ void route2(const Top2* __restrict__ top2, int* __restrict__ pos,
                       int* __restrict__ rows_list, float* __restrict__ wgt_list,
                       Slot2* __restrict__ slots) {
  __shared__ int lcnt[NE], lbase[NE];
  if (threadIdx.x < NE) lcnt[threadIdx.x] = 0;
  __syncthreads();
  const int r = blockIdx.x * 256 + threadIdx.x;
  Top2 tt = top2[r];
  int s0 = atomicAdd(&lcnt[tt.e0], 1);
  int s1 = atomicAdd(&lcnt[tt.e1], 1);
  __syncthreads();
  if (threadIdx.x < NE)
    lbase[threadIdx.x] = atomicAdd(&pos[threadIdx.x], lcnt[threadIdx.x]);
  __syncthreads();
  int p0 = lbase[tt.e0] + s0;
  rows_list[p0] = r; wgt_list[p0] = tt.w0;
  int p1 = lbase[tt.e1] + s1;
  rows_list[p1] = r; wgt_list[p1] = tt.w1;
  Slot2 sl; sl.p0 = p0; sl.p1 = p1;
  slots[r] = sl;
}

// ---------------- final combine: out[row] = pair[p0] + pair[p1]
__global__ __launch_bounds__(256)
void combine(const bf16* __restrict__ pairb, const Slot2* __restrict__ slots,
             float* __restrict__ out) {
  const int row = blockIdx.x;
  const Slot2 s = slots[row];
  const int t = threadIdx.x;
  const bf16x4 a = *(const bf16x4*)(pairb + (size_t)s.p0 * OD + t * 4);
  const bf16x4 b = *(const bf16x4*)(pairb + (size_t)s.p1 * OD + t * 4);
  f32x4 r;
#pragma unroll
  for (int j = 0; j < 4; ++j) r[j] = (float)a[j] + (float)b[j];
  *(f32x4*)(out + (size_t)row * OD + t * 4) = r;
}

// ========= 128x128 BK=64 SINGLE-buffered bf16 MFMA GEMM (m97 structure) =========
// C[128x128] = A[M][K] * BT[N][K]^T.  256 threads = 4 waves (2M x 2N), 64x64/wave.
// m97-proven shape: BK=64, one LDS buffer (32 KiB total -> 5 blocks/CU LDS-wise,
// VGPR-capped ~4), TWO barriers + one vmcnt(0) per 64-K step (half the events of
// the BK=32 loop); the vmcnt(0) drain is hidden by 4-5 co-resident blocks (m114).
// Swizzle for 8-granule rows: source/read octet ^= (row&7) -> a 16-lane b128
// phase covers 8 granule-slots x 2-way = conflict-free (m136).
// Fragments are read per-kk-half (8 live b128) to stay under the 128-VGPR cap.
// 1D grid XCD decode (r8-proven): A-tile's 8 N-blocks land on one XCD.
// MODE 0: proj -> combined (bf16, +bias)
// MODE 1: expert FFN1 (gathered A rows) -> h (bf16, +b1, relu)
// MODE 2: expert FFN2 -> pairbuf (bf16, w*(acc+b2))

#define BARe  do { __builtin_amdgcn_s_barrier(); __builtin_amdgcn_sched_barrier(0); } while (0)
#define VMC0  asm volatile("s_waitcnt vmcnt(0)" ::: "memory")
#define PRIO1 __builtin_amdgcn_s_setprio(1)
#define PRIO0 __builtin_amdgcn_s_setprio(0)

#define STAGE64(KT) do { \
  _Pragma("unroll") for (int j_ = 0; j_ < 4; ++j_) { \
    gload16(&As[ldso[j_]], aptr[j_] + (size_t)(KT) * 64); \
    gload16(&Bs[ldso[j_]], bptr[j_] + (size_t)(KT) * 64); \
  } \
} while (0)

template<int MODE>
__global__ __launch_bounds__(256, 4)
void gemm128(const bf16* __restrict__ A, const bf16* __restrict__ BT,
             const float* __restrict__ bias, bf16* __restrict__ outb,
             const int* __restrict__ rows_list, const float* __restrict__ wgt_list,
             const int* __restrict__ offsets, const int* __restrict__ padded,
             int K, int lda, int ldb, int ldout, int coloff) {
  __shared__ bf16 As[128 * 64];   // 16 KiB
  __shared__ bf16 Bs[128 * 64];   // 16 KiB
  const int t = threadIdx.x;
  const int lane = t & 63, w = t >> 6;
  const int wm = w >> 1, wn = w & 1;
  // XCD-aware decode (8 N-tiles in every GEMM here)
  const int bid = blockIdx.x;
  const int xcd = bid & 7, sdec = bid >> 3;
  const int nblk = sdec & 7, mblk = (sdec >> 3) * 8 + xcd;

  long base = 0;
  if constexpr (MODE != 0) {
    const int e = blockIdx.z;
    if (mblk * 128 >= padded[e]) return;
    base = offsets[e];
    if constexpr (MODE == 1) { BT += (size_t)e * HID * CB; bias += e * HID; }
    else                     { BT += (size_t)e * OD * HID; bias += e * OD; }
  }

  // staging: thread t, sub-load j (0..3): row = j*32 + (t>>3), granule c = t&7.
  // Row is 8 granules (128 B); source octet pre-swizzled: c ^ (row&7), where
  // row&7 == (t>>3)&7 for all j (j*32 = 0 mod 8). LDS dest linear (granule*16B).
  const int scol = ((t & 7) ^ ((t >> 3) & 7)) * 8;
  const bf16* aptr[4]; const bf16* bptr[4]; int ldso[4];
#pragma unroll
  for (int j = 0; j < 4; ++j) {
    const int row = j * 32 + (t >> 3);
    long ga;
    if constexpr (MODE == 1)      ga = rows_list[base + (long)mblk * 128 + row];
    else if constexpr (MODE == 2) ga = base + (long)mblk * 128 + row;
    else                          ga = (long)mblk * 128 + row;
    aptr[j] = A + ga * lda + scol;
    bptr[j] = BT + (size_t)(nblk * 128 + row) * ldb + scol;
    ldso[j] = (j * 256 + t) * 8;
  }

  // fragment reads (kk=0): row = base16 + fr; logical octet o = lane>>4 (0..3);
  // physical = o ^ (fr&7).  kk=1 flips octet bit2 -> element offset ^ 32.
  const int fr = lane & 15, hi = lane >> 4;
  const int rsw = hi ^ (fr & 7);
  int a_off[4], b_off[4];
#pragma unroll
  for (int f = 0; f < 4; ++f) {
    a_off[f] = ((wm * 64 + f * 16 + fr) * 8 + rsw) * 8;
    b_off[f] = ((wn * 64 + f * 16 + fr) * 8 + rsw) * 8;
  }

  f32x4 acc[4][4];
#pragma unroll
  for (int i = 0; i < 4; ++i)
#pragma unroll
    for (int j = 0; j < 4; ++j)
#pragma unroll
      for (int r = 0; r < 4; ++r) acc[i][j][r] = 0.0f;

  const int NKT = K >> 6;

  STAGE64(0);
  for (int kt = 0; kt < NKT; ++kt) {
    VMC0;                              // tile kt's 8 loads landed
    BARe;                              // visible to all waves
#pragma unroll
    for (int kk = 0; kk < 2; ++kk) {
      bf16x8 af[4], bfr[4];
#pragma unroll
      for (int f = 0; f < 4; ++f) af[f]  = *(const bf16x8*)(&As[a_off[f] ^ (kk * 32)]);
#pragma unroll
      for (int f = 0; f < 4; ++f) bfr[f] = *(const bf16x8*)(&Bs[b_off[f] ^ (kk * 32)]);
      PRIO1;
#pragma unroll
      for (int mf = 0; mf < 4; ++mf)
#pragma unroll
        for (int nf = 0; nf < 4; ++nf)
          acc[mf][nf] = __builtin_amdgcn_mfma_f32_16x16x32_bf16(af[mf], bfr[nf],
                                                                acc[mf][nf], 0, 0, 0);
      PRIO0;
    }
    BARe;                              // all waves done reading this buffer
    if (kt + 1 < NKT) STAGE64(kt + 1); // overwrite with next tile
  }

  // epilogue: D row = (lane>>4)*4 + r, col = lane&15
  const int row_h = hi * 4;
#pragma unroll
  for (int nf = 0; nf < 4; ++nf) {
    const int gcol = nblk * 128 + wn * 64 + nf * 16 + fr;
    const float bv = bias[gcol];
#pragma unroll
    for (int mf = 0; mf < 4; ++mf) {
      const int rbase = wm * 64 + mf * 16 + row_h;
#pragma unroll
      for (int r = 0; r < 4; ++r) {
        const int rit = rbase + r;
        float v = acc[mf][nf][r] + bv;
        if constexpr (MODE == 0) {
          outb[((size_t)mblk * 128 + rit) * ldout + coloff + gcol] = (bf16)v;
        } else if constexpr (MODE == 1) {
          outb[(size_t)(base + (long)mblk * 128 + rit) * ldout + gcol] =
              (bf16)fmaxf(v, 0.0f);
        } else {
          const long li = base + (long)mblk * 128 + rit;
          const float wgt = wgt_list[li];
          outb[(size_t)li * ldout + gcol] = (bf16)(wgt * v);
        }
      }
    }
  }
}

extern "C" void kernel_launch(void* const* d_in, const int* in_sizes, int n_in,
                              void* d_out, int out_size, void* d_ws, size_t ws_size,
                              hipStream_t stream) {
  const float* text  = (const float*)d_in[0];
  const float* image = (const float*)d_in[1];
  const float* noise = (const float*)d_in[2];
  const float* Wt    = (const float*)d_in[3];
  const float* bt    = (const float*)d_in[4];
  const float* Wi    = (const float*)d_in[5];
  const float* bi    = (const float*)d_in[6];
  const float* Wg    = (const float*)d_in[7];
  const float* bg    = (const float*)d_in[8];
  const float* W1    = (const float*)d_in[9];
  const float* b1    = (const float*)d_in[10];
  const float* W2    = (const float*)d_in[11];
  const float* b2    = (const float*)d_in[12];
  float* out = (float*)d_out;

  char* p = (char*)d_ws;
  auto alloc = [&](size_t bytes) {
    char* r = p; p += (bytes + 255) & ~(size_t)255; return r;
  };
  // union region: {text_b, image_b} (early) / pairbuf (late, after proj GEMMs)
  const size_t sz_text  = (size_t)BB * TD * 2;
  const size_t sz_texta = (sz_text + 255) & ~(size_t)255;
  const size_t sz_image = (size_t)BB * ID_ * 2;
  const size_t sz_pair  = (size_t)CAPT * OD * 2;
  size_t sz_u0 = sz_texta + sz_image;
  if (sz_pair > sz_u0) sz_u0 = sz_pair;
  char* u0 = alloc(sz_u0);
  bf16* text_b  = (bf16*)u0;
  bf16* image_b = (bf16*)(u0 + sz_texta);
  bf16* pairb   = (bf16*)u0;

  bf16*   WtT      = (bf16*)alloc((size_t)HID * TD * 2);
  bf16*   WiT      = (bf16*)alloc((size_t)HID * ID_ * 2);
  bf16*   W1T      = (bf16*)alloc((size_t)NE * HID * CB * 2);
  bf16*   W2T      = (bf16*)alloc((size_t)NE * OD * HID * 2);
  bf16*   combined = (bf16*)alloc((size_t)BB * CB * 2);
  bf16*   hbuf     = (bf16*)alloc((size_t)CAPT * HID * 2);
  double* WgF      = (double*)alloc((size_t)NE * GIN * 8);
  double* bgd      = (double*)alloc((size_t)NE * 8);
  Top2*   top2     = (Top2*)alloc((size_t)BB * sizeof(Top2));
  Slot2*  slots    = (Slot2*)alloc((size_t)BB * sizeof(Slot2));
  int*    counts   = (int*)alloc(NE * 4);
  int*    offsets  = (int*)alloc((NE + 1) * 4);
  int*    padded   = (int*)alloc(NE * 4);
  int*    pos      = (int*)alloc(NE * 4);
  int*    rows_list= (int*)alloc((size_t)CAPT * 4);
  float*  wgt_list = (float*)alloc((size_t)CAPT * 4);

  hipMemsetAsync(counts, 0, NE * 4, stream);

  transpose_cvt<<<dim3(HID / 64, TD / 64, 1),  256, 0, stream>>>(Wt, WtT, TD, HID);
  transpose_cvt<<<dim3(HID / 64, ID_ / 64, 1), 256, 0, stream>>>(Wi, WiT, ID_, HID);
  transpose_cvt<<<dim3(HID / 64, CB / 64, NE), 256, 0, stream>>>(W1, W1T, CB, HID);
  transpose_cvt<<<dim3(OD / 64, HID / 64, NE), 256, 0, stream>>>(W2, W2T, HID, OD);

  fuse_w<<<((GIN + 1) * NE + 255) / 256, 256, 0, stream>>>(
      Wt, Wi, Wg, bt, bi, bg, WgF, bgd);
  route1<<<BB / 64, 1024, 0, stream>>>(text, image, noise, WgF, bgd,
                                       text_b, image_b, top2, counts);
  scan_pad<<<1, 256, 0, stream>>>(counts, offsets, padded, pos, rows_list, wgt_list);
  route2<<<BB / 256, 256, 0, stream>>>(top2, pos, rows_list, wgt_list, slots);

  // proj: combined[:, :1024] = text @ Wt + bt ; combined[:, 1024:] = image @ Wi + bi
  // 1D grid: 128 mblk x 8 nblk = 1024 blocks, XCD-decoded in-kernel
  gemm128<0><<<dim3(1024, 1, 1), 256, 0, stream>>>(
      text_b, WtT, bt, combined, nullptr, nullptr, nullptr, nullptr,
      TD, TD, TD, CB, 0);
  gemm128<0><<<dim3(1024, 1, 1), 256, 0, stream>>>(
      image_b, WiT, bi, combined, nullptr, nullptr, nullptr, nullptr,
      ID_, ID_, ID_, CB, HID);
  // expert FFN1 (gathered) -> h   (128 mblk covers worst-case 16384 rows/expert)
  gemm128<1><<<dim3(1024, 1, NE), 256, 0, stream>>>(
      combined, W1T, b1, hbuf, rows_list, nullptr, offsets, padded,
      CB, CB, CB, HID, 0);
  // expert FFN2 -> pair buffer (plain bf16 stores)
  gemm128<2><<<dim3(1024, 1, NE), 256, 0, stream>>>(
      hbuf, W2T, b2, pairb, rows_list, wgt_list, offsets, padded,
      HID, HID, HID, OD, 0);
  // final: out[row] = pair[p0] + pair[p1]
  combine<<<BB, 256, 0, stream>>>(pairb, slots, out);
}